// Round 1
// baseline (204.369 us; speedup 1.0000x reference)
//
#include <hip/hip_runtime.h>
#include <hip/hip_bf16.h>
#include <math.h>

#define NS 2048
#define NR 512
#define ND 64
#define NH 8

typedef __attribute__((ext_vector_type(4))) float f4;
typedef __attribute__((ext_vector_type(4))) short s4;
typedef __attribute__((ext_vector_type(8))) short s8;

__device__ __forceinline__ short f2bf(float f) {
  unsigned u = __builtin_bit_cast(unsigned, f);
  u += 0x7fffu + ((u >> 16) & 1u);   // round-to-nearest-even
  return (short)(u >> 16);
}

// swizzled byte offset within a [rows][64] bf16 tile (128 B row stride).
// XOR of (row&7)<<4 keeps 16B alignment for 16B accesses (k multiples of 8)
// and spreads the 128B-stride column pattern across banks (<=2-way = free).
__device__ __forceinline__ int swz(int r, int c) {
  return ((r << 7) + (c << 1)) ^ ((r & 7) << 4);
}

__global__ __launch_bounds__(512, 2)
void ga_kernel(const float* __restrict__ gm, const float* __restrict__ gmask,
               const float* __restrict__ Wq, const float* __restrict__ Wk,
               const float* __restrict__ Wv, const float* __restrict__ Wg,
               const float* __restrict__ bg, const float* __restrict__ Wo,
               const float* __restrict__ bo, float* __restrict__ gout)
{
  __shared__ short m_bf[NR * ND];      // 64 KB bf16 copy of m[s], swizzled rows
  __shared__ float kvb[NR][16];        // 32 KB: [r][0..7]=k, [r][8..15]=v
  __shared__ float maskb[NR];          // 2 KB
  __shared__ union {                   // lifetime-disjoint buffers (16 KB)
    float poolb[32][ND];               // pool partials (early)
    float aatt[NH][NR];                // attention logits/probs (middle)
    short tmpb[8][16 * ND];            // per-wave gated 16x64 bf16 tile (late)
  } u;
  __shared__ float qv[ND];
  __shared__ float qh[ND];
  __shared__ float opart[8][ND];
  __shared__ float ofl[ND];
  __shared__ float denom_s;

  const int t    = threadIdx.x;
  const int lane = t & 63;
  const int wv   = t >> 6;             // wave 0..7
  const int s    = blockIdx.x;

  const float* mrow = gm + (size_t)s * NR * ND;

  // ---- mask row -> LDS ----
  for (int i = t; i < NR; i += 512) maskb[i] = gmask[(size_t)s * NR + i];
  __syncthreads();

  // ---- stream m[s]: fp32 pool partials + bf16 LDS tile ----
  const int g16 = t & 15;
  const int c0  = g16 * 4;             // this thread's fixed col quad
  const int rp  = t >> 4;              // 0..31 row phase
  f4 pool = {0.f, 0.f, 0.f, 0.f};
  #pragma unroll
  for (int i = 0; i < 16; ++i) {
    const int r = rp + 32 * i;
    const f4 mv = *reinterpret_cast<const f4*>(mrow + r * ND + c0);
    const float mk = maskb[r];
    pool.x += mv.x * mk; pool.y += mv.y * mk;
    pool.z += mv.z * mk; pool.w += mv.w * mk;
    s4 sv; sv.x = f2bf(mv.x); sv.y = f2bf(mv.y); sv.z = f2bf(mv.z); sv.w = f2bf(mv.w);
    *reinterpret_cast<s4*>(reinterpret_cast<char*>(m_bf) + swz(r, c0)) = sv;
  }
  *reinterpret_cast<f4*>(&u.poolb[rp][c0]) = pool;

  // ---- per-lane MFMA B-fragments (same for all blocks; L2-hot) ----
  // frag layout (16x16x32 bf16): B lane: col = lane&15, k = 8*(lane>>4)+j (+32*ks)
  const int bcol = lane & 15;
  const int kq   = (lane >> 4) * 8;
  s8 kvB[2], wgB[2][4], woB[2][4];
  {
    const float* Wsrc = (bcol < 8) ? (Wk + bcol) : (Wv + (bcol - 8));
    #pragma unroll
    for (int ks = 0; ks < 2; ++ks) {
      s8 f;
      #pragma unroll
      for (int jj = 0; jj < 8; ++jj) f[jj] = f2bf(Wsrc[(ks * 32 + kq + jj) * 8]);
      kvB[ks] = f;
    }
  }
  #pragma unroll
  for (int ks = 0; ks < 2; ++ks) {
    #pragma unroll
    for (int nt = 0; nt < 4; ++nt) {
      s8 fg, fo;
      #pragma unroll
      for (int jj = 0; jj < 8; ++jj) {
        const int k = ks * 32 + kq + jj;
        fg[jj] = f2bf(Wg[k * 64 + nt * 16 + bcol]);
        fo[jj] = f2bf(Wo[k * 64 + nt * 16 + bcol]);
      }
      wgB[ks][nt] = fg; woB[ks][nt] = fo;
    }
  }
  float bg_l[4], bo_l[4];
  #pragma unroll
  for (int nt = 0; nt < 4; ++nt) { bg_l[nt] = bg[nt * 16 + bcol]; bo_l[nt] = bo[nt * 16 + bcol]; }

  __syncthreads();                     // m_bf + poolb ready

  // ---- mask denom (wave 1, overlapped with K/V GEMM) ----
  if (wv == 1) {
    float p = 0.f;
    #pragma unroll
    for (int i = 0; i < 8; ++i) p += maskb[lane + 64 * i];
    #pragma unroll
    for (int off = 32; off; off >>= 1) p += __shfl_xor(p, off);
    if (lane == 0) denom_s = p + 1e-10f;
  }

  // ---- K/V GEMM via MFMA: [512x64] @ [64x16] ----
  // A frag: row = lane&15 (+r0), k = 8*(lane>>4)+j (+32*ks)
  // D frag: col = lane&15, row = 4*(lane>>4)+q   [m89-verified]
  const int arow = lane & 15;
  #pragma unroll
  for (int mt = 0; mt < 4; ++mt) {
    const int r0 = wv * 64 + mt * 16;
    f4 acc = {0.f, 0.f, 0.f, 0.f};
    #pragma unroll
    for (int ks = 0; ks < 2; ++ks) {
      const s8 aF = *reinterpret_cast<const s8*>(
          reinterpret_cast<const char*>(m_bf) + swz(r0 + arow, ks * 32 + kq));
      acc = __builtin_amdgcn_mfma_f32_16x16x32_bf16(aF, kvB[ks], acc, 0, 0, 0);
    }
    #pragma unroll
    for (int q = 0; q < 4; ++q) kvb[r0 + (lane >> 4) * 4 + q][bcol] = acc[q];
  }
  __syncthreads();                     // kvb + denom ready

  // ---- pooled query ----
  if (t < 64) {
    float ssum = 0.f;
    #pragma unroll
    for (int p = 0; p < 32; ++p) ssum += u.poolb[p][t];
    qv[t] = ssum / denom_s;
  }
  __syncthreads();
  if (t < 64) {
    float acc = 0.f;
    for (int c = 0; c < 64; ++c) acc += qv[c] * Wq[c * 64 + t];
    qh[t] = acc * 0.35355339059327373f;  // HEAD_DIM^-0.5
  }
  __syncthreads();

  // ---- logits: a[h][r] = qh[h,:] . k[r,:] + INF*(mask-1) ----
  {
    const int r = t;
    float kr[8];
    #pragma unroll
    for (int c = 0; c < 8; ++c) kr[c] = kvb[r][c];
    const float mterm = 1e9f * (maskb[r] - 1.0f);
    #pragma unroll
    for (int h = 0; h < NH; ++h) {
      float acc = 0.f;
      #pragma unroll
      for (int c = 0; c < 8; ++c) acc += qh[h * 8 + c] * kr[c];
      u.aatt[h][r] = acc + mterm;
    }
  }
  __syncthreads();

  // ---- softmax over r: wave wv owns head wv ----
  {
    float vals[8];
    float mx = -3.4e38f;
    #pragma unroll
    for (int i = 0; i < 8; ++i) { vals[i] = u.aatt[wv][lane + 64 * i]; mx = fmaxf(mx, vals[i]); }
    #pragma unroll
    for (int off = 32; off; off >>= 1) mx = fmaxf(mx, __shfl_xor(mx, off));
    float sum = 0.f;
    #pragma unroll
    for (int i = 0; i < 8; ++i) { vals[i] = __expf(vals[i] - mx); sum += vals[i]; }
    #pragma unroll
    for (int off = 32; off; off >>= 1) sum += __shfl_xor(sum, off);
    const float inv = 1.0f / sum;
    #pragma unroll
    for (int i = 0; i < 8; ++i) u.aatt[wv][lane + 64 * i] = vals[i] * inv;
  }
  __syncthreads();

  // ---- o[h][c] = sum_r a[h][r] * v[r][c] ----
  {
    const int ch = t >> 6, idx = t & 63, h = idx >> 3, c = idx & 7;
    float p = 0.f;
    #pragma unroll 8
    for (int rr = 0; rr < 64; ++rr) {
      const int r = ch * 64 + rr;
      p += u.aatt[h][r] * kvb[r][8 + c];
    }
    opart[ch][idx] = p;
  }
  __syncthreads();
  if (t < 64) {
    float sum = 0.f;
    #pragma unroll
    for (int ch = 0; ch < 8; ++ch) sum += opart[ch][t];
    ofl[t] = sum;
  }
  __syncthreads();                     // ofl ready; u.aatt dead -> u.tmpb usable

  // ---- phase B: per 16-row tile, gate GEMM + output GEMM ----
  float of_l[4];
  #pragma unroll
  for (int nt = 0; nt < 4; ++nt) of_l[nt] = ofl[nt * 16 + bcol];
  short* tmpw = &u.tmpb[wv][0];
  float* orow_base = gout + (size_t)s * NR * ND;
  const f4 zf = {0.f, 0.f, 0.f, 0.f};

  #pragma unroll
  for (int mt = 0; mt < 4; ++mt) {
    const int r0 = wv * 64 + mt * 16;

    // G = m_tile @ Wg  (16x64)
    f4 accG[4] = {zf, zf, zf, zf};
    #pragma unroll
    for (int ks = 0; ks < 2; ++ks) {
      const s8 aF = *reinterpret_cast<const s8*>(
          reinterpret_cast<const char*>(m_bf) + swz(r0 + arow, ks * 32 + kq));
      #pragma unroll
      for (int nt = 0; nt < 4; ++nt)
        accG[nt] = __builtin_amdgcn_mfma_f32_16x16x32_bf16(aF, wgB[ks][nt], accG[nt], 0, 0, 0);
    }

    // tmp = o_flat * sigmoid(G + bg)  -> bf16 tile in per-wave LDS
    #pragma unroll
    for (int nt = 0; nt < 4; ++nt) {
      #pragma unroll
      for (int q = 0; q < 4; ++q) {
        const float val = accG[nt][q] + bg_l[nt];
        const float gg = of_l[nt] / (1.0f + __expf(-val));
        const int row = (lane >> 4) * 4 + q;
        const int col = nt * 16 + bcol;
        *reinterpret_cast<short*>(reinterpret_cast<char*>(tmpw) + swz(row, col)) = f2bf(gg);
      }
    }
    asm volatile("s_waitcnt lgkmcnt(0)" ::: "memory");  // wave-internal RAW on tmpw

    // OUT = tmp @ Wo + bo  (16x64)
    f4 accO[4] = {zf, zf, zf, zf};
    #pragma unroll
    for (int ks = 0; ks < 2; ++ks) {
      const s8 aF = *reinterpret_cast<const s8*>(
          reinterpret_cast<const char*>(tmpw) + swz(arow, ks * 32 + kq));
      #pragma unroll
      for (int nt = 0; nt < 4; ++nt)
        accO[nt] = __builtin_amdgcn_mfma_f32_16x16x32_bf16(aF, woB[ks][nt], accO[nt], 0, 0, 0);
    }
    #pragma unroll
    for (int nt = 0; nt < 4; ++nt) {
      #pragma unroll
      for (int q = 0; q < 4; ++q) {
        const int row = r0 + (lane >> 4) * 4 + q;
        const int col = nt * 16 + bcol;
        orow_base[row * ND + col] = accO[nt][q] + bo_l[nt];
      }
    }
  }
}

extern "C" void kernel_launch(void* const* d_in, const int* in_sizes, int n_in,
                              void* d_out, int out_size, void* d_ws, size_t ws_size,
                              hipStream_t stream) {
  const float* m    = (const float*)d_in[0];
  const float* mask = (const float*)d_in[1];
  const float* Wq   = (const float*)d_in[2];
  const float* Wk   = (const float*)d_in[3];
  const float* Wv   = (const float*)d_in[4];
  const float* Wg   = (const float*)d_in[5];
  const float* bg   = (const float*)d_in[6];
  const float* Wo   = (const float*)d_in[7];
  const float* bo   = (const float*)d_in[8];
  float* out = (float*)d_out;
  ga_kernel<<<dim3(NS), dim3(512), 0, stream>>>(m, mask, Wq, Wk, Wv, Wg, bg, Wo, bo, out);
}

// Round 2
// 175.767 us; speedup vs baseline: 1.1627x; 1.1627x over previous
//
#include <hip/hip_runtime.h>
#include <hip/hip_bf16.h>
#include <math.h>

#define NS 2048
#define NR 512
#define ND 64
#define NH 8
#define NSLOT 18   // B-fragment slots: 2 kv + 8 wg + 8 wo

typedef __attribute__((ext_vector_type(4))) float f4;
typedef __attribute__((ext_vector_type(4))) short s4;
typedef __attribute__((ext_vector_type(8))) short s8;

__device__ __forceinline__ short f2bf(float f) {
  unsigned u = __builtin_bit_cast(unsigned, f);
  u += 0x7fffu + ((u >> 16) & 1u);   // round-to-nearest-even
  return (short)(u >> 16);
}

// swizzled byte offset within a [16][64] bf16 tile (128 B row stride)
__device__ __forceinline__ int swz(int r, int c) {
  return ((r << 7) + (c << 1)) ^ ((r & 7) << 4);
}

// ---- prep: pre-format bf16 B-fragments (lane-ordered) into d_ws ----
// slot layout: 0..1 = kv (ks), 2..9 = wg (ks*4+nt), 10..17 = wo (ks*4+nt)
// item i = slot*64+lane holds s8 at ws[i*8..i*8+8)
__global__ void prep_kernel(const float* __restrict__ Wk, const float* __restrict__ Wv,
                            const float* __restrict__ Wg, const float* __restrict__ Wo,
                            short* __restrict__ ws) {
  for (int i = threadIdx.x; i < NSLOT * 64; i += blockDim.x) {
    const int slot = i >> 6, lane = i & 63;
    const int col = lane & 15, kq = (lane >> 4) * 8;
    s8 f;
    if (slot < 2) {
      #pragma unroll
      for (int jj = 0; jj < 8; ++jj) {
        const int k = slot * 32 + kq + jj;
        f[jj] = f2bf(col < 8 ? Wk[k * 8 + col] : Wv[k * 8 + col - 8]);
      }
    } else if (slot < 10) {
      const int idx = slot - 2, ks = idx >> 2, nt = idx & 3;
      #pragma unroll
      for (int jj = 0; jj < 8; ++jj) {
        const int k = ks * 32 + kq + jj;
        f[jj] = f2bf(Wg[k * 64 + nt * 16 + col]);
      }
    } else {
      const int idx = slot - 10, ks = idx >> 2, nt = idx & 3;
      #pragma unroll
      for (int jj = 0; jj < 8; ++jj) {
        const int k = ks * 32 + kq + jj;
        f[jj] = f2bf(Wo[k * 64 + nt * 16 + col]);
      }
    }
    *reinterpret_cast<s8*>(ws + (size_t)i * 8) = f;
  }
}

__global__ __launch_bounds__(512, 4)
void ga_kernel(const float* __restrict__ gm, const float* __restrict__ gmask,
               const float* __restrict__ Wq, const float* __restrict__ bgp,
               const float* __restrict__ bop, const short* __restrict__ ws,
               float* __restrict__ gout)
{
  __shared__ short fragB[NSLOT * 64 * 8];  // 18 KB bf16 B-fragments
  __shared__ float kvb[NR][17];            // 34 KB (pad 17 kills write conflicts)
  __shared__ float maskb[NR];              // 2 KB
  __shared__ short tmpb[8][16 * ND];       // 16 KB per-wave gated tiles
  __shared__ float red[8][ND];             // 2 KB pool partials
  __shared__ float qv[ND];
  __shared__ float qh[ND];
  __shared__ float ofl[ND];
  __shared__ float denom_s;

  const int t    = threadIdx.x;
  const int lane = t & 63;
  const int wv   = t >> 6;
  const int s    = blockIdx.x;

  const int arow = lane & 15;            // A-frag row / D col ("bcol")
  const int g    = lane >> 4;            // k-quad group
  const int kq   = g * 8;
  const int bcol = arow;

  const float* mrow = gm + (size_t)s * NR * ND;

  // ---- stage 0: mask + fragB -> LDS ----
  for (int i = t; i < NR; i += 512) maskb[i] = gmask[(size_t)s * NR + i];
  for (int i = t; i < NSLOT * 64; i += 512)
    *reinterpret_cast<s8*>(&fragB[i * 8]) =
        *reinterpret_cast<const s8*>(ws + (size_t)i * 8);

  float bg_l[4], bo_l[4];
  #pragma unroll
  for (int nt = 0; nt < 4; ++nt) { bg_l[nt] = bgp[nt * 16 + bcol]; bo_l[nt] = bop[nt * 16 + bcol]; }

  __syncthreads();   // B1

  // ---- stage 1: stream m in fragment layout; pool in fp32; park bf16 in regs ----
  s8 mreg[4][2];
  f4 pA0 = {0,0,0,0}, pA1 = {0,0,0,0}, pB0 = {0,0,0,0}, pB1 = {0,0,0,0};
  #pragma unroll
  for (int mt = 0; mt < 4; ++mt) {
    const int row = wv * 64 + mt * 16 + arow;
    const float mk = maskb[row];
    const float* p = mrow + row * ND + kq;
    const f4 a0 = *reinterpret_cast<const f4*>(p);
    const f4 a1 = *reinterpret_cast<const f4*>(p + 4);
    const f4 b0 = *reinterpret_cast<const f4*>(p + 32);
    const f4 b1 = *reinterpret_cast<const f4*>(p + 36);
    pA0 += a0 * mk; pA1 += a1 * mk; pB0 += b0 * mk; pB1 += b1 * mk;
    s8 m0, m1;
    m0[0]=f2bf(a0.x); m0[1]=f2bf(a0.y); m0[2]=f2bf(a0.z); m0[3]=f2bf(a0.w);
    m0[4]=f2bf(a1.x); m0[5]=f2bf(a1.y); m0[6]=f2bf(a1.z); m0[7]=f2bf(a1.w);
    m1[0]=f2bf(b0.x); m1[1]=f2bf(b0.y); m1[2]=f2bf(b0.z); m1[3]=f2bf(b0.w);
    m1[4]=f2bf(b1.x); m1[5]=f2bf(b1.y); m1[6]=f2bf(b1.z); m1[7]=f2bf(b1.w);
    mreg[mt][0] = m0; mreg[mt][1] = m1;
  }
  // pool reduce over the 16 rows held by lanes differing in lane&15
  #pragma unroll
  for (int off = 8; off >= 1; off >>= 1) {
    pA0.x += __shfl_xor(pA0.x, off); pA0.y += __shfl_xor(pA0.y, off);
    pA0.z += __shfl_xor(pA0.z, off); pA0.w += __shfl_xor(pA0.w, off);
    pA1.x += __shfl_xor(pA1.x, off); pA1.y += __shfl_xor(pA1.y, off);
    pA1.z += __shfl_xor(pA1.z, off); pA1.w += __shfl_xor(pA1.w, off);
    pB0.x += __shfl_xor(pB0.x, off); pB0.y += __shfl_xor(pB0.y, off);
    pB0.z += __shfl_xor(pB0.z, off); pB0.w += __shfl_xor(pB0.w, off);
    pB1.x += __shfl_xor(pB1.x, off); pB1.y += __shfl_xor(pB1.y, off);
    pB1.z += __shfl_xor(pB1.z, off); pB1.w += __shfl_xor(pB1.w, off);
  }
  if (arow == 0) {
    *reinterpret_cast<f4*>(&red[wv][kq])      = pA0;
    *reinterpret_cast<f4*>(&red[wv][kq + 4])  = pA1;
    *reinterpret_cast<f4*>(&red[wv][32 + kq])     = pB0;
    *reinterpret_cast<f4*>(&red[wv][32 + kq + 4]) = pB1;
  }

  // mask denom (wave 7, overlapped)
  if (wv == 7) {
    float p = 0.f;
    #pragma unroll
    for (int i = 0; i < 8; ++i) p += maskb[lane + 64 * i];
    #pragma unroll
    for (int off = 32; off; off >>= 1) p += __shfl_xor(p, off);
    if (lane == 0) denom_s = p + 1e-10f;
  }

  // ---- K/V GEMM: [512x64]@[64x16] via MFMA, A from regs, B from fragB ----
  {
    const s8 kf0 = *reinterpret_cast<const s8*>(&fragB[(0 * 64 + lane) * 8]);
    const s8 kf1 = *reinterpret_cast<const s8*>(&fragB[(1 * 64 + lane) * 8]);
    #pragma unroll
    for (int mt = 0; mt < 4; ++mt) {
      f4 acc = {0,0,0,0};
      acc = __builtin_amdgcn_mfma_f32_16x16x32_bf16(mreg[mt][0], kf0, acc, 0, 0, 0);
      acc = __builtin_amdgcn_mfma_f32_16x16x32_bf16(mreg[mt][1], kf1, acc, 0, 0, 0);
      const int r0 = wv * 64 + mt * 16;
      #pragma unroll
      for (int q = 0; q < 4; ++q) kvb[r0 + g * 4 + q][bcol] = acc[q];
    }
  }
  __syncthreads();   // B2: kvb, red, denom ready

  // ---- pooled query ----
  if (t < 64) {
    float ssum = 0.f;
    #pragma unroll
    for (int p = 0; p < 8; ++p) ssum += red[p][t];
    qv[t] = ssum / denom_s;
  }
  __syncthreads();
  if (t < 64) {
    float acc = 0.f;
    for (int c = 0; c < 64; ++c) acc += qv[c] * Wq[c * 64 + t];
    qh[t] = acc * 0.35355339059327373f;  // HEAD_DIM^-0.5
  }
  __syncthreads();   // B4: qh ready

  // ---- logits + softmax + PV, fully in registers: wave wv owns head wv ----
  {
    float q0 = qh[wv * 8 + 0], q1 = qh[wv * 8 + 1], q2 = qh[wv * 8 + 2], q3 = qh[wv * 8 + 3];
    float q4 = qh[wv * 8 + 4], q5 = qh[wv * 8 + 5], q6 = qh[wv * 8 + 6], q7 = qh[wv * 8 + 7];
    float lg[8];
    float mx = -3.4e38f;
    #pragma unroll
    for (int i = 0; i < 8; ++i) {
      const int r = lane + 64 * i;
      const float* kr = &kvb[r][0];
      float acc = q0*kr[0] + q1*kr[1] + q2*kr[2] + q3*kr[3]
                + q4*kr[4] + q5*kr[5] + q6*kr[6] + q7*kr[7];
      lg[i] = acc + 1e9f * (maskb[r] - 1.0f);
      mx = fmaxf(mx, lg[i]);
    }
    #pragma unroll
    for (int off = 32; off; off >>= 1) mx = fmaxf(mx, __shfl_xor(mx, off));
    float sum = 0.f;
    #pragma unroll
    for (int i = 0; i < 8; ++i) { lg[i] = __expf(lg[i] - mx); sum += lg[i]; }
    #pragma unroll
    for (int off = 32; off; off >>= 1) sum += __shfl_xor(sum, off);
    const float inv = 1.0f / sum;
    float po[8] = {0,0,0,0,0,0,0,0};
    #pragma unroll
    for (int i = 0; i < 8; ++i) {
      const float a = lg[i] * inv;
      const float* vr = &kvb[lane + 64 * i][8];
      #pragma unroll
      for (int c = 0; c < 8; ++c) po[c] += a * vr[c];
    }
    #pragma unroll
    for (int off = 32; off; off >>= 1) {
      #pragma unroll
      for (int c = 0; c < 8; ++c) po[c] += __shfl_xor(po[c], off);
    }
    #pragma unroll
    for (int c = 0; c < 8; ++c) if (lane == c) ofl[wv * 8 + c] = po[c];
  }
  __syncthreads();   // B5: ofl ready

  // ---- phase B: per 16-row tile, gate GEMM + output GEMM ----
  float of_l[4];
  #pragma unroll
  for (int nt = 0; nt < 4; ++nt) of_l[nt] = ofl[nt * 16 + bcol];
  short* tmpw = &tmpb[wv][0];
  float* orow_base = gout + (size_t)s * NR * ND;
  const f4 zf = {0,0,0,0};

  #pragma unroll
  for (int mt = 0; mt < 4; ++mt) {
    const int r0 = wv * 64 + mt * 16;

    // G = m_tile @ Wg
    f4 accG[4] = {zf, zf, zf, zf};
    #pragma unroll
    for (int ks = 0; ks < 2; ++ks) {
      const s8 aF = mreg[mt][ks];
      #pragma unroll
      for (int nt = 0; nt < 4; ++nt) {
        const s8 wgF = *reinterpret_cast<const s8*>(&fragB[((2 + ks * 4 + nt) * 64 + lane) * 8]);
        accG[nt] = __builtin_amdgcn_mfma_f32_16x16x32_bf16(aF, wgF, accG[nt], 0, 0, 0);
      }
    }

    // tmp = o_flat * sigmoid(G + bg) -> bf16 per-wave LDS tile
    #pragma unroll
    for (int nt = 0; nt < 4; ++nt) {
      #pragma unroll
      for (int q = 0; q < 4; ++q) {
        const float val = accG[nt][q] + bg_l[nt];
        const float gg = of_l[nt] / (1.0f + __expf(-val));
        *reinterpret_cast<short*>(reinterpret_cast<char*>(tmpw) + swz(g * 4 + q, nt * 16 + bcol)) = f2bf(gg);
      }
    }
    asm volatile("s_waitcnt lgkmcnt(0)" ::: "memory");
    __builtin_amdgcn_sched_barrier(0);

    // OUT = tmp @ Wo + bo
    f4 accO[4] = {zf, zf, zf, zf};
    #pragma unroll
    for (int ks = 0; ks < 2; ++ks) {
      const s8 aF = *reinterpret_cast<const s8*>(
          reinterpret_cast<const char*>(tmpw) + swz(arow, ks * 32 + kq));
      #pragma unroll
      for (int nt = 0; nt < 4; ++nt) {
        const s8 woF = *reinterpret_cast<const s8*>(&fragB[((10 + ks * 4 + nt) * 64 + lane) * 8]);
        accO[nt] = __builtin_amdgcn_mfma_f32_16x16x32_bf16(aF, woF, accO[nt], 0, 0, 0);
      }
    }
    #pragma unroll
    for (int nt = 0; nt < 4; ++nt) {
      #pragma unroll
      for (int q = 0; q < 4; ++q) {
        const int row = r0 + g * 4 + q;
        orow_base[row * ND + nt * 16 + bcol] = accO[nt][q] + bo_l[nt];
      }
    }
  }
}

extern "C" void kernel_launch(void* const* d_in, const int* in_sizes, int n_in,
                              void* d_out, int out_size, void* d_ws, size_t ws_size,
                              hipStream_t stream) {
  const float* m    = (const float*)d_in[0];
  const float* mask = (const float*)d_in[1];
  const float* Wq   = (const float*)d_in[2];
  const float* Wk   = (const float*)d_in[3];
  const float* Wv   = (const float*)d_in[4];
  const float* Wg   = (const float*)d_in[5];
  const float* bg   = (const float*)d_in[6];
  const float* Wo   = (const float*)d_in[7];
  const float* bo   = (const float*)d_in[8];
  float* out = (float*)d_out;
  short* ws  = (short*)d_ws;

  prep_kernel<<<dim3(1), dim3(512), 0, stream>>>(Wk, Wv, Wg, Wo, ws);
  ga_kernel<<<dim3(NS), dim3(512), 0, stream>>>(m, mask, Wq, bg, bo, ws, out);
}

// Round 3
// 172.123 us; speedup vs baseline: 1.1873x; 1.0212x over previous
//
#include <hip/hip_runtime.h>
#include <hip/hip_bf16.h>
#include <math.h>

#define NS 2048
#define NR 512
#define ND 64
#define NH 8
#define NSLOT 18   // B-fragment slots: 2 kv + 8 wg + 8 wo

typedef __attribute__((ext_vector_type(4))) float f4;
typedef __attribute__((ext_vector_type(4))) unsigned u4;
typedef __attribute__((ext_vector_type(2))) unsigned u2;
typedef __attribute__((ext_vector_type(8))) short s8;

__device__ __forceinline__ short f2bf(float f) {
  unsigned u = __builtin_bit_cast(unsigned, f);
  u += 0x7fffu + ((u >> 16) & 1u);   // round-to-nearest-even
  return (short)(u >> 16);
}
__device__ __forceinline__ unsigned cvtpk(float lo, float hi) {
  unsigned r;
  asm("v_cvt_pk_bf16_f32 %0, %1, %2" : "=v"(r) : "v"(lo), "v"(hi));
  return r;
}
__device__ __forceinline__ float bflo(unsigned u) { return __builtin_bit_cast(float, u << 16); }
__device__ __forceinline__ float bfhi(unsigned u) { return __builtin_bit_cast(float, u & 0xffff0000u); }

// swizzled byte offset within a [16][64] bf16 tile (128 B row stride)
__device__ __forceinline__ int swz(int r, int c) {
  return ((r << 7) + (c << 1)) ^ ((r & 7) << 4);
}
// kv tile: [512][16] bf16 (32 B rows), XOR bit4 keyed on row bit2:
// b128 row reads conflict-free; D-frag scalar writes 2-way (free)
__device__ __forceinline__ int kvaddr(int r, int c) {
  return ((r << 5) + (c << 1)) ^ ((r & 4) << 2);
}

// ---- prep: pre-format bf16 B-fragments (lane-ordered) into d_ws ----
// slots: 0..1 = kv (ks); 2..9 = wg (ks*4+nt); 10..17 = wo (ks*4+nt)
// wg/wo are COLUMN-PERMUTED: slot-nt lane-col holds W[k][4*col+nt], so lane
// col's 4 accumulators are 4 consecutive output columns.
__global__ void prep_kernel(const float* __restrict__ Wk, const float* __restrict__ Wv,
                            const float* __restrict__ Wg, const float* __restrict__ Wo,
                            short* __restrict__ ws) {
  for (int i = threadIdx.x; i < NSLOT * 64; i += blockDim.x) {
    const int slot = i >> 6, lane = i & 63;
    const int col = lane & 15, kq = (lane >> 4) * 8;
    s8 f;
    if (slot < 2) {
      #pragma unroll
      for (int jj = 0; jj < 8; ++jj) {
        const int k = slot * 32 + kq + jj;
        f[jj] = f2bf(col < 8 ? Wk[k * 8 + col] : Wv[k * 8 + col - 8]);
      }
    } else if (slot < 10) {
      const int idx = slot - 2, ks = idx >> 2, nt = idx & 3;
      #pragma unroll
      for (int jj = 0; jj < 8; ++jj) {
        const int k = ks * 32 + kq + jj;
        f[jj] = f2bf(Wg[k * 64 + 4 * col + nt]);
      }
    } else {
      const int idx = slot - 10, ks = idx >> 2, nt = idx & 3;
      #pragma unroll
      for (int jj = 0; jj < 8; ++jj) {
        const int k = ks * 32 + kq + jj;
        f[jj] = f2bf(Wo[k * 64 + 4 * col + nt]);
      }
    }
    *reinterpret_cast<s8*>(ws + (size_t)i * 8) = f;
  }
}

__global__ __launch_bounds__(512, 8)
void ga_kernel(const float* __restrict__ gm, const float* __restrict__ gmask,
               const float* __restrict__ Wq, const float* __restrict__ bgp,
               const float* __restrict__ bop, const short* __restrict__ ws,
               float* __restrict__ gout)
{
  __shared__ short fragB[NSLOT * 64 * 8];          // 18 KB
  __shared__ union {
    unsigned short kv[NR][16];                     // 16 KB: [r][0..7]=k, [8..15]=v (bf16)
    short tmp[8][16 * ND];                         // 16 KB: per-wave gated tiles (phase B)
  } ukv;
  __shared__ float maskb[NR];                      // 2 KB
  __shared__ float red[8][ND];                     // 2 KB
  __shared__ float qv[ND];
  __shared__ float qh[ND];
  __shared__ float ofl[ND];
  __shared__ float denom_s;

  const int t    = threadIdx.x;
  const int lane = t & 63;
  const int wv   = t >> 6;
  const int s    = blockIdx.x;

  const int arow = lane & 15;   // A-frag row / D col
  const int g    = lane >> 4;   // k-quad group
  const int kq   = g * 8;
  const int bcol = arow;

  const float* mrow = gm + (size_t)s * NR * ND;

  // ---- stage 0: mask + fragB -> LDS ----
  for (int i = t; i < NR; i += 512) maskb[i] = gmask[(size_t)s * NR + i];
  for (int i = t; i < NSLOT * 64; i += 512)
    *reinterpret_cast<s8*>(&fragB[i * 8]) =
        *reinterpret_cast<const s8*>(ws + (size_t)i * 8);
  __syncthreads();   // B1

  // ---- stream m in fragment layout; fp32 pool; park bf16 frags in regs ----
  s8 mreg[4][2];
  f4 pA0 = {0,0,0,0}, pA1 = {0,0,0,0}, pB0 = {0,0,0,0}, pB1 = {0,0,0,0};
  #pragma unroll
  for (int mt = 0; mt < 4; ++mt) {
    const int row = wv * 64 + mt * 16 + arow;
    const float mk = maskb[row];
    const float* p = mrow + row * ND + kq;
    const f4 a0 = *reinterpret_cast<const f4*>(p);
    const f4 a1 = *reinterpret_cast<const f4*>(p + 4);
    const f4 b0 = *reinterpret_cast<const f4*>(p + 32);
    const f4 b1 = *reinterpret_cast<const f4*>(p + 36);
    pA0 += a0 * mk; pA1 += a1 * mk; pB0 += b0 * mk; pB1 += b1 * mk;
    u4 ua, ub;
    ua[0] = cvtpk(a0.x, a0.y); ua[1] = cvtpk(a0.z, a0.w);
    ua[2] = cvtpk(a1.x, a1.y); ua[3] = cvtpk(a1.z, a1.w);
    ub[0] = cvtpk(b0.x, b0.y); ub[1] = cvtpk(b0.z, b0.w);
    ub[2] = cvtpk(b1.x, b1.y); ub[3] = cvtpk(b1.z, b1.w);
    mreg[mt][0] = __builtin_bit_cast(s8, ua);
    mreg[mt][1] = __builtin_bit_cast(s8, ub);
  }
  // reduce pool over the 16 rows spread across lanes differing in lane&15
  #pragma unroll
  for (int off = 8; off >= 1; off >>= 1) {
    pA0.x += __shfl_xor(pA0.x, off); pA0.y += __shfl_xor(pA0.y, off);
    pA0.z += __shfl_xor(pA0.z, off); pA0.w += __shfl_xor(pA0.w, off);
    pA1.x += __shfl_xor(pA1.x, off); pA1.y += __shfl_xor(pA1.y, off);
    pA1.z += __shfl_xor(pA1.z, off); pA1.w += __shfl_xor(pA1.w, off);
    pB0.x += __shfl_xor(pB0.x, off); pB0.y += __shfl_xor(pB0.y, off);
    pB0.z += __shfl_xor(pB0.z, off); pB0.w += __shfl_xor(pB0.w, off);
    pB1.x += __shfl_xor(pB1.x, off); pB1.y += __shfl_xor(pB1.y, off);
    pB1.z += __shfl_xor(pB1.z, off); pB1.w += __shfl_xor(pB1.w, off);
  }
  if (arow == 0) {
    *reinterpret_cast<f4*>(&red[wv][kq])          = pA0;
    *reinterpret_cast<f4*>(&red[wv][kq + 4])      = pA1;
    *reinterpret_cast<f4*>(&red[wv][32 + kq])     = pB0;
    *reinterpret_cast<f4*>(&red[wv][32 + kq + 4]) = pB1;
  }
  if (wv == 7) {   // mask denom, overlapped
    float p = 0.f;
    #pragma unroll
    for (int i = 0; i < 8; ++i) p += maskb[lane + 64 * i];
    #pragma unroll
    for (int off = 32; off; off >>= 1) p += __shfl_xor(p, off);
    if (lane == 0) denom_s = p + 1e-10f;
  }

  // ---- K/V GEMM: [512x64]@[64x16], A regs, B fragB; D -> bf16 kv tile ----
  {
    const s8 kf0 = *reinterpret_cast<const s8*>(&fragB[(0 * 64 + lane) * 8]);
    const s8 kf1 = *reinterpret_cast<const s8*>(&fragB[(1 * 64 + lane) * 8]);
    #pragma unroll
    for (int mt = 0; mt < 4; ++mt) {
      f4 acc = {0,0,0,0};
      acc = __builtin_amdgcn_mfma_f32_16x16x32_bf16(mreg[mt][0], kf0, acc, 0, 0, 0);
      acc = __builtin_amdgcn_mfma_f32_16x16x32_bf16(mreg[mt][1], kf1, acc, 0, 0, 0);
      const int r0 = wv * 64 + mt * 16;
      #pragma unroll
      for (int q = 0; q < 4; ++q)
        *reinterpret_cast<unsigned short*>(
            reinterpret_cast<char*>(ukv.kv) + kvaddr(r0 + g * 4 + q, bcol)) =
            (unsigned short)f2bf(acc[q]);
    }
  }
  __syncthreads();   // B2: kv, red, denom ready

  // ---- pooled query (parallelized) ----
  if (t < 64) {
    float ss = 0.f;
    #pragma unroll
    for (int p = 0; p < 8; ++p) ss += red[p][t];
    qv[t] = ss;                       // un-normalized pool
  }
  __syncthreads();   // B3
  {
    float acc = 0.f;
    #pragma unroll
    for (int j = 0; j < 8; ++j) acc += qv[wv * 8 + j] * Wq[(wv * 8 + j) * 64 + lane];
    red[wv][lane] = acc;              // red reused for Wq partials
  }
  __syncthreads();   // B4
  if (t < 64) {
    float ss = 0.f;
    #pragma unroll
    for (int p = 0; p < 8; ++p) ss += red[p][t];
    qh[t] = ss * 0.35355339059327373f / denom_s;   // fold pool-denom into scale
  }
  __syncthreads();   // B5

  // ---- logits + softmax + PV in registers: wave wv owns head wv ----
  {
    const float q0 = qh[wv * 8 + 0], q1 = qh[wv * 8 + 1], q2 = qh[wv * 8 + 2], q3 = qh[wv * 8 + 3];
    const float q4 = qh[wv * 8 + 4], q5 = qh[wv * 8 + 5], q6 = qh[wv * 8 + 6], q7 = qh[wv * 8 + 7];
    float lg[8];
    float mx = -3.4e38f;
    #pragma unroll
    for (int i = 0; i < 8; ++i) {
      const int r = lane + 64 * i;
      const u4 kk = *reinterpret_cast<const u4*>(
          reinterpret_cast<const char*>(ukv.kv) + (((r << 5)) ^ ((r & 4) << 2)));
      float acc = q0 * bflo(kk[0]) + q1 * bfhi(kk[0])
                + q2 * bflo(kk[1]) + q3 * bfhi(kk[1])
                + q4 * bflo(kk[2]) + q5 * bfhi(kk[2])
                + q6 * bflo(kk[3]) + q7 * bfhi(kk[3]);
      lg[i] = acc + 1e9f * (maskb[r] - 1.0f);
      mx = fmaxf(mx, lg[i]);
    }
    #pragma unroll
    for (int off = 32; off; off >>= 1) mx = fmaxf(mx, __shfl_xor(mx, off));
    float sum = 0.f;
    #pragma unroll
    for (int i = 0; i < 8; ++i) { lg[i] = __expf(lg[i] - mx); sum += lg[i]; }
    #pragma unroll
    for (int off = 32; off; off >>= 1) sum += __shfl_xor(sum, off);
    const float inv = 1.0f / sum;
    float po[8] = {0,0,0,0,0,0,0,0};
    #pragma unroll
    for (int i = 0; i < 8; ++i) {
      const int r = lane + 64 * i;
      const float a = lg[i] * inv;
      const u4 vvv = *reinterpret_cast<const u4*>(
          reinterpret_cast<const char*>(ukv.kv) + (((r << 5) + 16) ^ ((r & 4) << 2)));
      po[0] += a * bflo(vvv[0]); po[1] += a * bfhi(vvv[0]);
      po[2] += a * bflo(vvv[1]); po[3] += a * bfhi(vvv[1]);
      po[4] += a * bflo(vvv[2]); po[5] += a * bfhi(vvv[2]);
      po[6] += a * bflo(vvv[3]); po[7] += a * bfhi(vvv[3]);
    }
    #pragma unroll
    for (int off = 32; off; off >>= 1) {
      #pragma unroll
      for (int c = 0; c < 8; ++c) po[c] += __shfl_xor(po[c], off);
    }
    #pragma unroll
    for (int c = 0; c < 8; ++c) if (lane == c) ofl[wv * 8 + c] = po[c];
  }
  __syncthreads();   // B6: ofl ready; kv dead -> tmp usable

  // ---- phase B: gate GEMM + output GEMM, 4 consecutive out-cols per lane ----
  float of_l[4], bg_l[4], bo_l[4];
  #pragma unroll
  for (int nt = 0; nt < 4; ++nt) {
    of_l[nt] = ofl[4 * bcol + nt];
    bg_l[nt] = bgp[4 * bcol + nt];
    bo_l[nt] = bop[4 * bcol + nt];
  }
  short* tmpw = &ukv.tmp[wv][0];
  float* orow_base = gout + (size_t)s * NR * ND;
  const f4 zf = {0,0,0,0};

  #pragma unroll
  for (int mt = 0; mt < 4; ++mt) {
    const int r0 = wv * 64 + mt * 16;

    // G = m_tile @ Wg'  (col-permuted)
    f4 accG[4] = {zf, zf, zf, zf};
    #pragma unroll
    for (int ks = 0; ks < 2; ++ks) {
      const s8 aF = mreg[mt][ks];
      #pragma unroll
      for (int nt = 0; nt < 4; ++nt) {
        const s8 wgF = *reinterpret_cast<const s8*>(&fragB[((2 + ks * 4 + nt) * 64 + lane) * 8]);
        accG[nt] = __builtin_amdgcn_mfma_f32_16x16x32_bf16(aF, wgF, accG[nt], 0, 0, 0);
      }
    }

    // tmp = o * sigmoid(G + bg) -> bf16 tile via packed 8B writes
    #pragma unroll
    for (int q = 0; q < 4; ++q) {
      float v[4];
      #pragma unroll
      for (int nt = 0; nt < 4; ++nt) {
        const float val = accG[nt][q] + bg_l[nt];
        v[nt] = of_l[nt] / (1.0f + __expf(-val));
      }
      u2 w;
      w[0] = cvtpk(v[0], v[1]);
      w[1] = cvtpk(v[2], v[3]);
      *reinterpret_cast<u2*>(reinterpret_cast<char*>(tmpw) + swz(g * 4 + q, 4 * bcol)) = w;
    }
    asm volatile("s_waitcnt lgkmcnt(0)" ::: "memory");
    __builtin_amdgcn_sched_barrier(0);

    // OUT = tmp @ Wo' + bo ; lane stores 4 consecutive cols as dwordx4
    f4 accO[4] = {zf, zf, zf, zf};
    #pragma unroll
    for (int ks = 0; ks < 2; ++ks) {
      const s8 aF = *reinterpret_cast<const s8*>(
          reinterpret_cast<const char*>(tmpw) + swz(arow, ks * 32 + kq));
      #pragma unroll
      for (int nt = 0; nt < 4; ++nt) {
        const s8 woF = *reinterpret_cast<const s8*>(&fragB[((10 + ks * 4 + nt) * 64 + lane) * 8]);
        accO[nt] = __builtin_amdgcn_mfma_f32_16x16x32_bf16(aF, woF, accO[nt], 0, 0, 0);
      }
    }
    #pragma unroll
    for (int q = 0; q < 4; ++q) {
      f4 ov;
      ov.x = accO[0][q] + bo_l[0];
      ov.y = accO[1][q] + bo_l[1];
      ov.z = accO[2][q] + bo_l[2];
      ov.w = accO[3][q] + bo_l[3];
      *reinterpret_cast<f4*>(orow_base + (r0 + g * 4 + q) * ND + 4 * bcol) = ov;
    }
  }
}

extern "C" void kernel_launch(void* const* d_in, const int* in_sizes, int n_in,
                              void* d_out, int out_size, void* d_ws, size_t ws_size,
                              hipStream_t stream) {
  const float* m    = (const float*)d_in[0];
  const float* mask = (const float*)d_in[1];
  const float* Wq   = (const float*)d_in[2];
  const float* Wk   = (const float*)d_in[3];
  const float* Wv   = (const float*)d_in[4];
  const float* Wg   = (const float*)d_in[5];
  const float* bg   = (const float*)d_in[6];
  const float* Wo   = (const float*)d_in[7];
  const float* bo   = (const float*)d_in[8];
  float* out = (float*)d_out;
  short* ws  = (short*)d_ws;

  prep_kernel<<<dim3(1), dim3(512), 0, stream>>>(Wk, Wv, Wg, Wo, ws);
  ga_kernel<<<dim3(NS), dim3(512), 0, stream>>>(m, mask, Wq, bg, bo, ws, out);
}

// Round 4
// 152.829 us; speedup vs baseline: 1.3372x; 1.1262x over previous
//
#include <hip/hip_runtime.h>
#include <hip/hip_bf16.h>
#include <math.h>

#define NS 2048
#define NR 512
#define ND 64
#define NH 8
#define NSLOT 18   // B-fragment slots: 2 kv + 8 wg + 8 wo

typedef __attribute__((ext_vector_type(4))) float f4;
typedef __attribute__((ext_vector_type(4))) unsigned u4;
typedef __attribute__((ext_vector_type(2))) unsigned u2;
typedef __attribute__((ext_vector_type(8))) short s8;

__device__ __forceinline__ short f2bf(float f) {
  unsigned u = __builtin_bit_cast(unsigned, f);
  u += 0x7fffu + ((u >> 16) & 1u);   // round-to-nearest-even
  return (short)(u >> 16);
}
__device__ __forceinline__ unsigned cvtpk(float lo, float hi) {
  unsigned r;
  asm("v_cvt_pk_bf16_f32 %0, %1, %2" : "=v"(r) : "v"(lo), "v"(hi));
  return r;
}
__device__ __forceinline__ float bflo(unsigned u) { return __builtin_bit_cast(float, u << 16); }
__device__ __forceinline__ float bfhi(unsigned u) { return __builtin_bit_cast(float, u & 0xffff0000u); }

// swizzled byte offset within a [16][64] bf16 tile (128 B row stride)
__device__ __forceinline__ int swz(int r, int c) {
  return ((r << 7) + (c << 1)) ^ ((r & 7) << 4);
}
// kv tile: [512][16] bf16 (32 B rows); XOR bit4 keyed on row bit2 makes the
// attention phase's per-row b128 reads (64 lanes, 64 different rows) hit all
// 32 banks uniformly.
__device__ __forceinline__ int kvaddr(int r, int c) {
  return ((r << 5) + (c << 1)) ^ ((r & 4) << 2);
}

// ---- prep: pre-format bf16 B-fragments (lane-ordered) into d_ws ----
// slots: 0..1 = kv (ks); 2..9 = wg (ks*4+nt); 10..17 = wo (ks*4+nt)
// wg/wo are COLUMN-PERMUTED: slot-nt lane-col holds W[k][4*col+nt], so a
// lane's 4 accumulators are 4 consecutive output columns.
__global__ void prep_kernel(const float* __restrict__ Wk, const float* __restrict__ Wv,
                            const float* __restrict__ Wg, const float* __restrict__ Wo,
                            short* __restrict__ ws) {
  for (int i = threadIdx.x; i < NSLOT * 64; i += blockDim.x) {
    const int slot = i >> 6, lane = i & 63;
    const int col = lane & 15, kq = (lane >> 4) * 8;
    s8 f;
    if (slot < 2) {
      #pragma unroll
      for (int jj = 0; jj < 8; ++jj) {
        const int k = slot * 32 + kq + jj;
        f[jj] = f2bf(col < 8 ? Wk[k * 8 + col] : Wv[k * 8 + col - 8]);
      }
    } else if (slot < 10) {
      const int idx = slot - 2, ks = idx >> 2, nt = idx & 3;
      #pragma unroll
      for (int jj = 0; jj < 8; ++jj) {
        const int k = ks * 32 + kq + jj;
        f[jj] = f2bf(Wg[k * 64 + 4 * col + nt]);
      }
    } else {
      const int idx = slot - 10, ks = idx >> 2, nt = idx & 3;
      #pragma unroll
      for (int jj = 0; jj < 8; ++jj) {
        const int k = ks * 32 + kq + jj;
        f[jj] = f2bf(Wo[k * 64 + 4 * col + nt]);
      }
    }
    *reinterpret_cast<s8*>(ws + (size_t)i * 8) = f;
  }
}

__global__ __launch_bounds__(512, 6)
void ga_kernel(const float* __restrict__ gm, const float* __restrict__ gmask,
               const float* __restrict__ Wq, const float* __restrict__ bgp,
               const float* __restrict__ bop, const short* __restrict__ ws,
               float* __restrict__ gout)
{
  __shared__ short fragB[NSLOT * 64 * 8];          // 18 KB
  __shared__ union {
    unsigned short kv[NR][16];                     // 16 KB (phase A/attention)
    short tmp[8][16 * ND];                         // 16 KB (phase B, per-wave)
  } ukv;
  __shared__ float maskb[NR];                      // 2 KB
  __shared__ float red[8][ND];                     // 2 KB pool partials
  __shared__ float ofl[ND];                        // 256 B
  __shared__ float bgo[2][ND];                     // 512 B staged bg, bo

  const int t    = threadIdx.x;
  const int lane = t & 63;
  const int wv   = t >> 6;
  const int s    = blockIdx.x;

  const int arow = lane & 15;   // A-frag row / D col
  const int g    = lane >> 4;   // k-quad group
  const int kq   = g * 8;

  const float* mrow = gm + (size_t)s * NR * ND;

  // ---- stage 0: mask + fragB + bg/bo -> LDS ----
  for (int i = t; i < NR; i += 512) maskb[i] = gmask[(size_t)s * NR + i];
  for (int i = t; i < NSLOT * 64; i += 512)
    *reinterpret_cast<s8*>(&fragB[i * 8]) =
        *reinterpret_cast<const s8*>(ws + (size_t)i * 8);
  if (t < 64)            bgo[0][t]      = bgp[t];
  else if (t < 128)      bgo[1][t - 64] = bop[t - 64];
  __syncthreads();   // B1

  // ---- phase A: stream m; fp32 masked pool; K/V GEMM (convert inline) ----
  f4 pA0 = {0,0,0,0}, pA1 = {0,0,0,0}, pB0 = {0,0,0,0}, pB1 = {0,0,0,0};
  #pragma unroll
  for (int mt = 0; mt < 4; ++mt) {
    const int row = wv * 64 + mt * 16 + arow;
    const float mk = maskb[row];
    const float* p = mrow + row * ND + kq;
    const f4 a0 = *reinterpret_cast<const f4*>(p);
    const f4 a1 = *reinterpret_cast<const f4*>(p + 4);
    const f4 b0 = *reinterpret_cast<const f4*>(p + 32);
    const f4 b1 = *reinterpret_cast<const f4*>(p + 36);
    pA0 += a0 * mk; pA1 += a1 * mk; pB0 += b0 * mk; pB1 += b1 * mk;
    u4 ua, ub;
    ua[0] = cvtpk(a0.x, a0.y); ua[1] = cvtpk(a0.z, a0.w);
    ua[2] = cvtpk(a1.x, a1.y); ua[3] = cvtpk(a1.z, a1.w);
    ub[0] = cvtpk(b0.x, b0.y); ub[1] = cvtpk(b0.z, b0.w);
    ub[2] = cvtpk(b1.x, b1.y); ub[3] = cvtpk(b1.z, b1.w);
    const s8 mA = __builtin_bit_cast(s8, ua);
    const s8 mB = __builtin_bit_cast(s8, ub);
    const s8 kf0 = *reinterpret_cast<const s8*>(&fragB[(0 * 64 + lane) * 8]);
    const s8 kf1 = *reinterpret_cast<const s8*>(&fragB[(1 * 64 + lane) * 8]);
    f4 acc = {0,0,0,0};
    acc = __builtin_amdgcn_mfma_f32_16x16x32_bf16(mA, kf0, acc, 0, 0, 0);
    acc = __builtin_amdgcn_mfma_f32_16x16x32_bf16(mB, kf1, acc, 0, 0, 0);
    const int r0 = wv * 64 + mt * 16;
    #pragma unroll
    for (int q = 0; q < 4; ++q)
      *reinterpret_cast<unsigned short*>(
          reinterpret_cast<char*>(ukv.kv) + kvaddr(r0 + g * 4 + q, arow)) =
          (unsigned short)f2bf(acc[q]);
  }
  // reduce pool over the 16 rows spread across lanes differing in lane&15
  #pragma unroll
  for (int off = 8; off >= 1; off >>= 1) {
    pA0.x += __shfl_xor(pA0.x, off); pA0.y += __shfl_xor(pA0.y, off);
    pA0.z += __shfl_xor(pA0.z, off); pA0.w += __shfl_xor(pA0.w, off);
    pA1.x += __shfl_xor(pA1.x, off); pA1.y += __shfl_xor(pA1.y, off);
    pA1.z += __shfl_xor(pA1.z, off); pA1.w += __shfl_xor(pA1.w, off);
    pB0.x += __shfl_xor(pB0.x, off); pB0.y += __shfl_xor(pB0.y, off);
    pB0.z += __shfl_xor(pB0.z, off); pB0.w += __shfl_xor(pB0.w, off);
    pB1.x += __shfl_xor(pB1.x, off); pB1.y += __shfl_xor(pB1.y, off);
    pB1.z += __shfl_xor(pB1.z, off); pB1.w += __shfl_xor(pB1.w, off);
  }
  if (arow == 0) {
    *reinterpret_cast<f4*>(&red[wv][kq])          = pA0;
    *reinterpret_cast<f4*>(&red[wv][kq + 4])      = pA1;
    *reinterpret_cast<f4*>(&red[wv][32 + kq])     = pB0;
    *reinterpret_cast<f4*>(&red[wv][32 + kq + 4]) = pB1;
  }
  __syncthreads();   // B2: kv + red ready

  // ---- prefetch phase-B mt=0 m tile (hides HBM latency under q+attention) --
  f4 pf0, pf1, pf2, pf3;
  {
    const float* p = mrow + (wv * 64 + arow) * ND + kq;
    pf0 = *reinterpret_cast<const f4*>(p);
    pf1 = *reinterpret_cast<const f4*>(p + 4);
    pf2 = *reinterpret_cast<const f4*>(p + 32);
    pf3 = *reinterpret_cast<const f4*>(p + 36);
  }

  // ---- per-wave redundant q: pool-normalize, @Wq, scale (no barriers) ----
  float q0, q1, q2, q3, q4, q5, q6, q7;
  {
    float qv_l = 0.f;
    #pragma unroll
    for (int p = 0; p < 8; ++p) qv_l += red[p][lane];
    float dn = 0.f;
    #pragma unroll
    for (int i = 0; i < 8; ++i) dn += maskb[lane + 64 * i];
    #pragma unroll
    for (int off = 32; off; off >>= 1) dn += __shfl_xor(dn, off);
    const f4 w0 = *reinterpret_cast<const f4*>(Wq + lane * 64 + wv * 8);
    const f4 w1 = *reinterpret_cast<const f4*>(Wq + lane * 64 + wv * 8 + 4);
    float a0 = qv_l * w0.x, a1 = qv_l * w0.y, a2 = qv_l * w0.z, a3 = qv_l * w0.w;
    float a4 = qv_l * w1.x, a5 = qv_l * w1.y, a6 = qv_l * w1.z, a7 = qv_l * w1.w;
    #pragma unroll
    for (int off = 32; off; off >>= 1) {
      a0 += __shfl_xor(a0, off); a1 += __shfl_xor(a1, off);
      a2 += __shfl_xor(a2, off); a3 += __shfl_xor(a3, off);
      a4 += __shfl_xor(a4, off); a5 += __shfl_xor(a5, off);
      a6 += __shfl_xor(a6, off); a7 += __shfl_xor(a7, off);
    }
    const float qs = 0.35355339059327373f / (dn + 1e-10f);
    q0 = a0 * qs; q1 = a1 * qs; q2 = a2 * qs; q3 = a3 * qs;
    q4 = a4 * qs; q5 = a5 * qs; q6 = a6 * qs; q7 = a7 * qs;
  }

  // ---- logits + softmax + PV in registers: wave wv owns head wv ----
  {
    float lg[8];
    float mx = -3.4e38f;
    #pragma unroll
    for (int i = 0; i < 8; ++i) {
      const int r = lane + 64 * i;
      const u4 kk = *reinterpret_cast<const u4*>(
          reinterpret_cast<const char*>(ukv.kv) + ((r << 5) ^ ((r & 4) << 2)));
      float acc = q0 * bflo(kk[0]) + q1 * bfhi(kk[0])
                + q2 * bflo(kk[1]) + q3 * bfhi(kk[1])
                + q4 * bflo(kk[2]) + q5 * bfhi(kk[2])
                + q6 * bflo(kk[3]) + q7 * bfhi(kk[3]);
      lg[i] = acc + 1e9f * (maskb[r] - 1.0f);
      mx = fmaxf(mx, lg[i]);
    }
    #pragma unroll
    for (int off = 32; off; off >>= 1) mx = fmaxf(mx, __shfl_xor(mx, off));
    float sum = 0.f;
    #pragma unroll
    for (int i = 0; i < 8; ++i) { lg[i] = __expf(lg[i] - mx); sum += lg[i]; }
    #pragma unroll
    for (int off = 32; off; off >>= 1) sum += __shfl_xor(sum, off);
    const float inv = 1.0f / sum;
    float po[8] = {0,0,0,0,0,0,0,0};
    #pragma unroll
    for (int i = 0; i < 8; ++i) {
      const int r = lane + 64 * i;
      const float a = lg[i] * inv;
      const u4 vvv = *reinterpret_cast<const u4*>(
          reinterpret_cast<const char*>(ukv.kv) + (((r << 5) + 16) ^ ((r & 4) << 2)));
      po[0] += a * bflo(vvv[0]); po[1] += a * bfhi(vvv[0]);
      po[2] += a * bflo(vvv[1]); po[3] += a * bfhi(vvv[1]);
      po[4] += a * bflo(vvv[2]); po[5] += a * bfhi(vvv[2]);
      po[6] += a * bflo(vvv[3]); po[7] += a * bfhi(vvv[3]);
    }
    #pragma unroll
    for (int off = 32; off; off >>= 1) {
      #pragma unroll
      for (int c = 0; c < 8; ++c) po[c] += __shfl_xor(po[c], off);
    }
    #pragma unroll
    for (int c = 0; c < 8; ++c) if (lane == c) ofl[wv * 8 + c] = po[c];
  }
  __syncthreads();   // B3: ofl ready; kv dead -> tmp usable

  // ---- phase B: re-stream m; gate GEMM + output GEMM per 16-row tile ----
  short* tmpw = &ukv.tmp[wv][0];
  float* orow_base = gout + (size_t)s * NR * ND;
  const f4 zf = {0,0,0,0};

  #pragma unroll
  for (int mt = 0; mt < 4; ++mt) {
    const int r0 = wv * 64 + mt * 16;
    f4 a0, a1, b0, b1;
    if (mt == 0) { a0 = pf0; a1 = pf1; b0 = pf2; b1 = pf3; }
    else {
      const float* p = mrow + (r0 + arow) * ND + kq;
      a0 = *reinterpret_cast<const f4*>(p);
      a1 = *reinterpret_cast<const f4*>(p + 4);
      b0 = *reinterpret_cast<const f4*>(p + 32);
      b1 = *reinterpret_cast<const f4*>(p + 36);
    }
    u4 ua, ub;
    ua[0] = cvtpk(a0.x, a0.y); ua[1] = cvtpk(a0.z, a0.w);
    ua[2] = cvtpk(a1.x, a1.y); ua[3] = cvtpk(a1.z, a1.w);
    ub[0] = cvtpk(b0.x, b0.y); ub[1] = cvtpk(b0.z, b0.w);
    ub[2] = cvtpk(b1.x, b1.y); ub[3] = cvtpk(b1.z, b1.w);
    const s8 mA = __builtin_bit_cast(s8, ua);
    const s8 mB = __builtin_bit_cast(s8, ub);

    // G = m_tile @ Wg' (col-permuted)
    f4 accG[4] = {zf, zf, zf, zf};
    #pragma unroll
    for (int nt = 0; nt < 4; ++nt) {
      const s8 wg0 = *reinterpret_cast<const s8*>(&fragB[((2 + nt) * 64 + lane) * 8]);
      const s8 wg1 = *reinterpret_cast<const s8*>(&fragB[((6 + nt) * 64 + lane) * 8]);
      accG[nt] = __builtin_amdgcn_mfma_f32_16x16x32_bf16(mA, wg0, accG[nt], 0, 0, 0);
      accG[nt] = __builtin_amdgcn_mfma_f32_16x16x32_bf16(mB, wg1, accG[nt], 0, 0, 0);
    }

    // tmp = o * sigmoid(G + bg) -> bf16 tile (o/bg broadcast-read from LDS)
    const f4 ofv = *reinterpret_cast<const f4*>(&ofl[4 * arow]);
    const f4 bgv = *reinterpret_cast<const f4*>(&bgo[0][4 * arow]);
    #pragma unroll
    for (int q = 0; q < 4; ++q) {
      float v[4];
      #pragma unroll
      for (int nt = 0; nt < 4; ++nt)
        v[nt] = ofv[nt] / (1.0f + __expf(-(accG[nt][q] + bgv[nt])));
      u2 w;
      w[0] = cvtpk(v[0], v[1]);
      w[1] = cvtpk(v[2], v[3]);
      *reinterpret_cast<u2*>(reinterpret_cast<char*>(tmpw) + swz(g * 4 + q, 4 * arow)) = w;
    }
    asm volatile("s_waitcnt lgkmcnt(0)" ::: "memory");
    __builtin_amdgcn_sched_barrier(0);

    // OUT = tmp @ Wo' + bo ; lane stores 4 consecutive cols as dwordx4
    f4 accO[4] = {zf, zf, zf, zf};
    #pragma unroll
    for (int ks = 0; ks < 2; ++ks) {
      const s8 aF = *reinterpret_cast<const s8*>(
          reinterpret_cast<const char*>(tmpw) + swz(arow, ks * 32 + kq));
      #pragma unroll
      for (int nt = 0; nt < 4; ++nt) {
        const s8 woF = *reinterpret_cast<const s8*>(&fragB[((10 + ks * 4 + nt) * 64 + lane) * 8]);
        accO[nt] = __builtin_amdgcn_mfma_f32_16x16x32_bf16(aF, woF, accO[nt], 0, 0, 0);
      }
    }
    const f4 bov = *reinterpret_cast<const f4*>(&bgo[1][4 * arow]);
    #pragma unroll
    for (int q = 0; q < 4; ++q) {
      f4 ov;
      ov.x = accO[0][q] + bov.x;
      ov.y = accO[1][q] + bov.y;
      ov.z = accO[2][q] + bov.z;
      ov.w = accO[3][q] + bov.w;
      *reinterpret_cast<f4*>(orow_base + (r0 + g * 4 + q) * ND + 4 * arow) = ov;
    }
  }
}

extern "C" void kernel_launch(void* const* d_in, const int* in_sizes, int n_in,
                              void* d_out, int out_size, void* d_ws, size_t ws_size,
                              hipStream_t stream) {
  const float* m    = (const float*)d_in[0];
  const float* mask = (const float*)d_in[1];
  const float* Wq   = (const float*)d_in[2];
  const float* Wk   = (const float*)d_in[3];
  const float* Wv   = (const float*)d_in[4];
  const float* Wg   = (const float*)d_in[5];
  const float* bg   = (const float*)d_in[6];
  const float* Wo   = (const float*)d_in[7];
  const float* bo   = (const float*)d_in[8];
  float* out = (float*)d_out;
  short* ws  = (short*)d_ws;

  prep_kernel<<<dim3(1), dim3(512), 0, stream>>>(Wk, Wv, Wg, Wo, ws);
  ga_kernel<<<dim3(NS), dim3(512), 0, stream>>>(m, mask, Wq, bg, bo, ws, out);
}